// Round 1
// baseline (311.642 us; speedup 1.0000x reference)
//
#include <hip/hip_runtime.h>
#include <cstddef>

// Problem constants
#define BB 4
#define CCH 256     // C
#define C2 128      // C/2
#define NN 4096     // T*H*W
#define PM 384      // 3*C2 (stacked Q,K,V projection rows)

// ---------------- pack Wq/Wk/Wv + biases into one [384x256] matrix ----------
__global__ __launch_bounds__(256) void k_pack(
    const float* __restrict__ Wq, const float* __restrict__ bq,
    const float* __restrict__ Wk, const float* __restrict__ bk,
    const float* __restrict__ Wv, const float* __restrict__ bv,
    float* __restrict__ wpack, float* __restrict__ bpack)
{
    const int m = blockIdx.x;     // 0..383
    const int c = threadIdx.x;    // 0..255
    const float* w; const float* bs; int mm;
    if (m < C2)        { w = Wq; bs = bq; mm = m; }
    else if (m < 2*C2) { w = Wk; bs = bk; mm = m - C2; }
    else               { w = Wv; bs = bv; mm = m - 2*C2; }
    wpack[m * CCH + c] = w[mm * CCH + c];
    if (c == 0) bpack[m] = bs[mm];
}

// ---------------- QKV projection: qkv[b][m][n] = sum_c wpack[m][c]*(X+pe)[b][c][n]
//                  + bpack[m] + task_sel[m%128][n] ------------------------------
// Tile: BM=128, BN=128, BK=16; 256 threads; 8x8 micro-tile per thread.
__global__ __launch_bounds__(256) void k_proj(
    const float* __restrict__ X, const float* __restrict__ pe,
    const float* __restrict__ tq, const float* __restrict__ tk,
    const float* __restrict__ tv,
    const float* __restrict__ wpack, const float* __restrict__ bpack,
    float* __restrict__ qkv)
{
    __shared__ float As[16][128];   // [k][m]
    __shared__ float Bs[16][128];   // [k][n]
    const int b  = blockIdx.z;
    const int m0 = blockIdx.y * 128;   // 0,128,256
    const int n0 = blockIdx.x * 128;
    const int tid = threadIdx.x;
    const int ty = tid >> 4, tx = tid & 15;
    const float* __restrict__ Xb = X + (size_t)b * CCH * NN;

    float acc[8][8];
#pragma unroll
    for (int i = 0; i < 8; ++i)
#pragma unroll
        for (int j = 0; j < 8; ++j) acc[i][j] = 0.f;

    const int am = tid >> 1;           // A row loaded by this thread (0..127)
    const int ak = (tid & 1) * 8;      // A col base (2 float4s)
    const int bk_ = tid >> 4;          // B row kk (0..15)
    const int bn  = (tid & 15) * 8;    // B col base (2 float4s)

    for (int k0 = 0; k0 < CCH; k0 += 16) {
        // A tile (transposed into [k][m])
        float4 a0 = *(const float4*)&wpack[(size_t)(m0 + am) * CCH + k0 + ak];
        float4 a1 = *(const float4*)&wpack[(size_t)(m0 + am) * CCH + k0 + ak + 4];
        As[ak+0][am] = a0.x; As[ak+1][am] = a0.y; As[ak+2][am] = a0.z; As[ak+3][am] = a0.w;
        As[ak+4][am] = a1.x; As[ak+5][am] = a1.y; As[ak+6][am] = a1.z; As[ak+7][am] = a1.w;
        // B tile: Xp = X + pe
        {
            const size_t rb = (size_t)(k0 + bk_) * NN + n0 + bn;
            float4 x0 = *(const float4*)&Xb[rb];
            float4 x1 = *(const float4*)&Xb[rb + 4];
            float4 p0 = *(const float4*)&pe[rb];
            float4 p1 = *(const float4*)&pe[rb + 4];
            float4 r0, r1;
            r0.x = x0.x + p0.x; r0.y = x0.y + p0.y; r0.z = x0.z + p0.z; r0.w = x0.w + p0.w;
            r1.x = x1.x + p1.x; r1.y = x1.y + p1.y; r1.z = x1.z + p1.z; r1.w = x1.w + p1.w;
            *(float4*)&Bs[bk_][bn]     = r0;
            *(float4*)&Bs[bk_][bn + 4] = r1;
        }
        __syncthreads();
#pragma unroll
        for (int kk = 0; kk < 16; ++kk) {
            float4 av0 = *(const float4*)&As[kk][ty * 8];
            float4 av1 = *(const float4*)&As[kk][ty * 8 + 4];
            float4 bv0 = *(const float4*)&Bs[kk][tx * 8];
            float4 bv1 = *(const float4*)&Bs[kk][tx * 8 + 4];
            float a[8] = {av0.x, av0.y, av0.z, av0.w, av1.x, av1.y, av1.z, av1.w};
            float bb[8] = {bv0.x, bv0.y, bv0.z, bv0.w, bv1.x, bv1.y, bv1.z, bv1.w};
#pragma unroll
            for (int ii = 0; ii < 8; ++ii)
#pragma unroll
                for (int jj = 0; jj < 8; ++jj)
                    acc[ii][jj] += a[ii] * bb[jj];
        }
        __syncthreads();
    }

    // epilogue: + bias + task
    const int sel = m0 >> 7;   // 0->q, 1->k, 2->v (BM=128 aligned with groups)
    const float* __restrict__ task = (sel == 0) ? tq : ((sel == 1) ? tk : tv);
#pragma unroll
    for (int ii = 0; ii < 8; ++ii) {
        const int m = m0 + ty * 8 + ii;
        const float bia = bpack[m];
        const int mr = m & (C2 - 1);
#pragma unroll
        for (int jj = 0; jj < 8; jj += 4) {
            const int n = n0 + tx * 8 + jj;
            float4 tsk = *(const float4*)&task[(size_t)mr * NN + n];
            float4 o;
            o.x = acc[ii][jj+0] + bia + tsk.x;
            o.y = acc[ii][jj+1] + bia + tsk.y;
            o.z = acc[ii][jj+2] + bia + tsk.z;
            o.w = acc[ii][jj+3] + bia + tsk.w;
            *(float4*)&qkv[((size_t)b * PM + m) * NN + n] = o;
        }
    }
}

// ---------------- M[b][i][j] = sum_n K[b][i][n] * V[b][j][n] ----------------
// grid (64 n-slices, B); each block reduces a 64-wide n slice, atomicAdd into M.
__global__ __launch_bounds__(256) void k_kv(
    const float* __restrict__ qkv, float* __restrict__ Mb)
{
    __shared__ float Ks[64][128];   // [nn][i]
    __shared__ float Vs[64][128];   // [nn][j]
    const int b = blockIdx.y;
    const int n0 = blockIdx.x * 64;
    const int tid = threadIdx.x;
    const int r = tid >> 1;              // row i/j (0..127)
    const int nb = (tid & 1) * 32;       // nn base
    const float* __restrict__ Kg = qkv + ((size_t)b * PM + C2) * NN;
    const float* __restrict__ Vg = qkv + ((size_t)b * PM + 2 * C2) * NN;
#pragma unroll
    for (int s = 0; s < 8; ++s) {
        const int nn = nb + s * 4;
        float4 kv = *(const float4*)&Kg[(size_t)r * NN + n0 + nn];
        Ks[nn+0][r] = kv.x; Ks[nn+1][r] = kv.y; Ks[nn+2][r] = kv.z; Ks[nn+3][r] = kv.w;
        float4 vv = *(const float4*)&Vg[(size_t)r * NN + n0 + nn];
        Vs[nn+0][r] = vv.x; Vs[nn+1][r] = vv.y; Vs[nn+2][r] = vv.z; Vs[nn+3][r] = vv.w;
    }
    __syncthreads();
    const int ti = tid >> 4, tj = tid & 15;
    float acc[8][8];
#pragma unroll
    for (int i = 0; i < 8; ++i)
#pragma unroll
        for (int j = 0; j < 8; ++j) acc[i][j] = 0.f;
    for (int nn = 0; nn < 64; ++nn) {
        float4 a0 = *(const float4*)&Ks[nn][ti * 8];
        float4 a1 = *(const float4*)&Ks[nn][ti * 8 + 4];
        float4 b0 = *(const float4*)&Vs[nn][tj * 8];
        float4 b1 = *(const float4*)&Vs[nn][tj * 8 + 4];
        float a[8] = {a0.x, a0.y, a0.z, a0.w, a1.x, a1.y, a1.z, a1.w};
        float v[8] = {b0.x, b0.y, b0.z, b0.w, b1.x, b1.y, b1.z, b1.w};
#pragma unroll
        for (int ii = 0; ii < 8; ++ii)
#pragma unroll
            for (int jj = 0; jj < 8; ++jj)
                acc[ii][jj] += a[ii] * v[jj];
    }
    float* __restrict__ Mp = Mb + (size_t)b * C2 * C2;
#pragma unroll
    for (int ii = 0; ii < 8; ++ii)
#pragma unroll
        for (int jj = 0; jj < 8; ++jj)
            atomicAdd(&Mp[(ti * 8 + ii) * C2 + tj * 8 + jj], acc[ii][jj]);
}

// ---------------- out3[b][n][j] = sum_i Q[b][i][n] * M[b][i][j] -------------
// grid (64 n-tiles, 2 j-halves, B)
__global__ __launch_bounds__(256) void k_qm(
    const float* __restrict__ qkv, const float* __restrict__ Mb,
    float* __restrict__ out3)
{
    __shared__ float Qs[128][64];   // [i][n_local]
    __shared__ float Ms[128][64];   // [i][j_local]
    const int b = blockIdx.z;
    const int nbase = blockIdx.x * 64;
    const int jbase = blockIdx.y * 64;
    const int tid = threadIdx.x;
    const int r = tid >> 1;               // i (0..127)
    const int cb = (tid & 1) * 32;
    const float* __restrict__ Qg = qkv + (size_t)b * PM * NN;
    const float* __restrict__ Mg = Mb + (size_t)b * C2 * C2;
#pragma unroll
    for (int s = 0; s < 8; ++s) {
        const int cc = cb + s * 4;
        *(float4*)&Qs[r][cc] = *(const float4*)&Qg[(size_t)r * NN + nbase + cc];
        *(float4*)&Ms[r][cc] = *(const float4*)&Mg[r * C2 + jbase + cc];
    }
    __syncthreads();
    const int tn = tid >> 4, tj = tid & 15;
    float acc[4][4];
#pragma unroll
    for (int i = 0; i < 4; ++i)
#pragma unroll
        for (int j = 0; j < 4; ++j) acc[i][j] = 0.f;
    for (int i = 0; i < 128; ++i) {
        float4 a  = *(const float4*)&Qs[i][tn * 4];
        float4 m4 = *(const float4*)&Ms[i][tj * 4];
        float av[4] = {a.x, a.y, a.z, a.w};
        float mv[4] = {m4.x, m4.y, m4.z, m4.w};
#pragma unroll
        for (int ii = 0; ii < 4; ++ii)
#pragma unroll
            for (int jj = 0; jj < 4; ++jj)
                acc[ii][jj] += av[ii] * mv[jj];
    }
#pragma unroll
    for (int ii = 0; ii < 4; ++ii) {
        float4 o;
        o.x = acc[ii][0]; o.y = acc[ii][1]; o.z = acc[ii][2]; o.w = acc[ii][3];
        *(float4*)&out3[((size_t)b * NN + nbase + tn * 4 + ii) * C2 + jbase + tj * 4] = o;
    }
}

// ---------------- final: out[b][o][p] = X[b][o][p]
//   + sum_c Wo[o][c] * out3[b][c*32 + (p>>7)][p&127] ------------------------
// grid (32 g, 2 o-halves, B); block computes [128 o][128 j] for p = g*128+j
__global__ __launch_bounds__(256) void k_final(
    const float* __restrict__ out3, const float* __restrict__ Wo,
    const float* __restrict__ X, float* __restrict__ out)
{
    __shared__ float Ds[64][128];    // [c_local][j]
    __shared__ float Wos[64][128];   // [c_local][o_local]
    const int g  = blockIdx.x;        // 0..31
    const int o0 = blockIdx.y * 128;  // 0 or 128
    const int b  = blockIdx.z;
    const int tid = threadIdx.x;
    const int to = tid >> 4, tj = tid & 15;
    float acc[8][8];
#pragma unroll
    for (int i = 0; i < 8; ++i)
#pragma unroll
        for (int j = 0; j < 8; ++j) acc[i][j] = 0.f;

    const float* __restrict__ O3 = out3 + (size_t)b * NN * C2;

    for (int ch = 0; ch < 2; ++ch) {
        const int c0 = ch * 64;
        // load D tile: rows are the gathered out3 rows c*32+g
        {
            const int r  = tid >> 2;             // c_local 0..63
            const int jb2 = (tid & 3) * 32;
#pragma unroll
            for (int s = 0; s < 8; ++s) {
                const int j = jb2 + s * 4;
                *(float4*)&Ds[r][j] =
                    *(const float4*)&O3[(size_t)((c0 + r) * 32 + g) * C2 + j];
            }
        }
        // load Wo tile transposed
        {
            const int o  = tid >> 1;             // o_local 0..127
            const int cb2 = (tid & 1) * 32;
#pragma unroll
            for (int s = 0; s < 8; ++s) {
                const int cc = cb2 + s * 4;
                float4 w = *(const float4*)&Wo[(size_t)(o0 + o) * C2 + c0 + cc];
                Wos[cc+0][o] = w.x; Wos[cc+1][o] = w.y;
                Wos[cc+2][o] = w.z; Wos[cc+3][o] = w.w;
            }
        }
        __syncthreads();
#pragma unroll
        for (int cc = 0; cc < 64; ++cc) {
            float4 w0 = *(const float4*)&Wos[cc][to * 8];
            float4 w1 = *(const float4*)&Wos[cc][to * 8 + 4];
            float4 d0 = *(const float4*)&Ds[cc][tj * 8];
            float4 d1 = *(const float4*)&Ds[cc][tj * 8 + 4];
            float w[8] = {w0.x, w0.y, w0.z, w0.w, w1.x, w1.y, w1.z, w1.w};
            float d[8] = {d0.x, d0.y, d0.z, d0.w, d1.x, d1.y, d1.z, d1.w};
#pragma unroll
            for (int ii = 0; ii < 8; ++ii)
#pragma unroll
                for (int jj = 0; jj < 8; ++jj)
                    acc[ii][jj] += w[ii] * d[jj];
        }
        __syncthreads();
    }

    const float* __restrict__ Xb = X + (size_t)b * CCH * NN;
    float* __restrict__ Ob = out + (size_t)b * CCH * NN;
#pragma unroll
    for (int oo = 0; oo < 8; ++oo) {
        const int o = o0 + to * 8 + oo;
        const size_t base = (size_t)o * NN + g * 128 + tj * 8;
        float4 x0 = *(const float4*)&Xb[base];
        float4 x1 = *(const float4*)&Xb[base + 4];
        float4 r0, r1;
        r0.x = acc[oo][0] + x0.x; r0.y = acc[oo][1] + x0.y;
        r0.z = acc[oo][2] + x0.z; r0.w = acc[oo][3] + x0.w;
        r1.x = acc[oo][4] + x1.x; r1.y = acc[oo][5] + x1.y;
        r1.z = acc[oo][6] + x1.z; r1.w = acc[oo][7] + x1.w;
        *(float4*)&Ob[base]     = r0;
        *(float4*)&Ob[base + 4] = r1;
    }
}

extern "C" void kernel_launch(void* const* d_in, const int* in_sizes, int n_in,
                              void* d_out, int out_size, void* d_ws, size_t ws_size,
                              hipStream_t stream) {
    const float* X  = (const float*)d_in[0];
    const float* pe = (const float*)d_in[1];
    const float* tq = (const float*)d_in[2];
    const float* tk = (const float*)d_in[3];
    const float* tv = (const float*)d_in[4];
    const float* Wq = (const float*)d_in[5];
    const float* bq = (const float*)d_in[6];
    const float* Wk = (const float*)d_in[7];
    const float* bk = (const float*)d_in[8];
    const float* Wv = (const float*)d_in[9];
    const float* bv = (const float*)d_in[10];
    const float* Wo = (const float*)d_in[11];
    float* out = (float*)d_out;

    float* ws    = (float*)d_ws;
    float* wpack = ws;                       // 384*256      = 98304
    float* bpack = ws + 98304;               // 384
    float* qkv   = ws + 98688;               // 4*384*4096   = 6291456
    float* Mbuf  = ws + 98688 + 6291456;     // 4*128*128    = 65536
    float* out3  = ws + 6455680;             // 4*4096*128   = 2097152

    hipMemsetAsync(Mbuf, 0, (size_t)BB * C2 * C2 * sizeof(float), stream);

    k_pack<<<dim3(PM), dim3(256), 0, stream>>>(Wq, bq, Wk, bk, Wv, bv, wpack, bpack);
    k_proj<<<dim3(NN / 128, PM / 128, BB), dim3(256), 0, stream>>>(
        X, pe, tq, tk, tv, wpack, bpack, qkv);
    k_kv<<<dim3(NN / 64, BB), dim3(256), 0, stream>>>(qkv, Mbuf);
    k_qm<<<dim3(NN / 64, 2, BB), dim3(256), 0, stream>>>(qkv, Mbuf, out3);
    k_final<<<dim3(32, 2, BB), dim3(256), 0, stream>>>(out3, Wo, X, out);
}

// Round 4
// 169.684 us; speedup vs baseline: 1.8366x; 1.8366x over previous
//
#include <hip/hip_runtime.h>
#include <cstddef>

// Problem constants
#define BB 4
#define CCH 256     // C
#define C2 128      // C/2
#define NN 4096     // T*H*W
#define PM 384      // 3*C2 (stacked Q,K,V projection rows)
#define KVS 32      // split-n slices for K*V^T (128 n each)

typedef __attribute__((ext_vector_type(8))) short short8v;   // 8 bf16 (4 VGPRs)
typedef __attribute__((ext_vector_type(4))) short short4v;   // 4 bf16 (8B)
typedef __attribute__((ext_vector_type(4))) float f32x4;

static __device__ __forceinline__ short f2bf(float f) {
    union { float f; unsigned u; } c; c.f = f;
    unsigned r = (c.u + 0x7FFFu + ((c.u >> 16) & 1u)) >> 16;
    return (short)r;
}

// ---------------- pack Wq/Wk/Wv (as bf16) + biases ----------
__global__ __launch_bounds__(256) void k_pack(
    const float* __restrict__ Wq, const float* __restrict__ bq,
    const float* __restrict__ Wk, const float* __restrict__ bk,
    const float* __restrict__ Wv, const float* __restrict__ bv,
    short* __restrict__ wpackh, float* __restrict__ bpack)
{
    const int m = blockIdx.x;     // 0..383
    const int c = threadIdx.x;    // 0..255
    const float* w; const float* bs; int mm;
    if (m < C2)        { w = Wq; bs = bq; mm = m; }
    else if (m < 2*C2) { w = Wk; bs = bk; mm = m - C2; }
    else               { w = Wv; bs = bv; mm = m - 2*C2; }
    wpackh[m * CCH + c] = f2bf(w[mm * CCH + c]);
    if (c == 0) bpack[m] = bs[mm];
}

// ---------------- QKV projection via bf16 MFMA ------------------------------
// qkv[b][m][n] = sum_c W[m][c]*(X+pe)[c][n] + bias[m] + task[m%128][n]
// Block: 256 thr (4 waves, 2x2 wave grid), tile 128m x 128n, K-step 32.
// LDS tiles stored [row][k] with rows padded to 40 shorts (80 B) -> <=2-way
// bank conflicts on both the transpose writes and the b128 fragment reads.
#define LROW 40
__global__ __launch_bounds__(256) void k_projm(
    const float* __restrict__ X, const float* __restrict__ pe,
    const float* __restrict__ tq, const float* __restrict__ tk,
    const float* __restrict__ tv,
    const short* __restrict__ wpackh, const float* __restrict__ bpack,
    float* __restrict__ qkv)
{
    __shared__ short As[128 * LROW];   // [m_local][k] bf16
    __shared__ short Bs[128 * LROW];   // [n_local][k] bf16
    const int b  = blockIdx.z;
    const int m0 = blockIdx.y * 128;   // 0,128,256
    const int n0 = blockIdx.x * 128;
    const int tid  = threadIdx.x;
    const int wave = tid >> 6;
    const int lane = tid & 63;
    const int lr = lane & 15, lg = lane >> 4;
    const int wm = wave >> 1, wn = wave & 1;     // 2x2 wave grid (64m x 64n each)
    const float* __restrict__ Xb = X + (size_t)b * CCH * NN;

    // staging coords
    const int am  = tid >> 1;         // A: m row 0..127
    const int akb = tid & 1;          // A: 16-short half (0: k 0..15, 1: k 16..31)
    const int cq = tid >> 5;          // B: c-quad 0..7 (4 c rows each)
    const int nq = tid & 31;          // B: n-quad 0..31 (4 n each)

    f32x4 acc[4][4];
#pragma unroll
    for (int i = 0; i < 4; ++i)
#pragma unroll
        for (int j = 0; j < 4; ++j) acc[i][j] = (f32x4){0.f, 0.f, 0.f, 0.f};

    for (int k0 = 0; k0 < CCH; k0 += 32) {
        // ---- stage A: 128m x 32k bf16 (each thread: 16 shorts = full coverage)
        {
            const size_t gsrc = (size_t)(m0 + am) * CCH + k0 + akb * 16;
            *(short8v*)&As[am * LROW + akb * 16] =
                *(const short8v*)&wpackh[gsrc];
            *(short8v*)&As[am * LROW + akb * 16 + 8] =
                *(const short8v*)&wpackh[gsrc + 8];
        }
        // ---- stage B: transpose 32c x 128n of (X+pe) -> [n][k] bf16
        short sreg[4][4];   // [j=c][i=n]
#pragma unroll
        for (int j = 0; j < 4; ++j) {
            const int c = k0 + cq * 4 + j;
            const size_t g = (size_t)c * NN + n0 + nq * 4;
            float4 x4 = *(const float4*)&Xb[g];
            float4 p4 = *(const float4*)&pe[g];
            sreg[j][0] = f2bf(x4.x + p4.x);
            sreg[j][1] = f2bf(x4.y + p4.y);
            sreg[j][2] = f2bf(x4.z + p4.z);
            sreg[j][3] = f2bf(x4.w + p4.w);
        }
#pragma unroll
        for (int i = 0; i < 4; ++i) {
            short4v v; v.x = sreg[0][i]; v.y = sreg[1][i]; v.z = sreg[2][i]; v.w = sreg[3][i];
            *(short4v*)&Bs[(nq * 4 + i) * LROW + cq * 4] = v;
        }
        __syncthreads();
        // ---- MFMA: 4x4 fragments of 16x16; lane l holds k=(l>>4)*8+j
        short8v a[4], bfr[4];
#pragma unroll
        for (int fm = 0; fm < 4; ++fm)
            a[fm] = *(const short8v*)&As[(wm * 64 + fm * 16 + lr) * LROW + lg * 8];
#pragma unroll
        for (int fn = 0; fn < 4; ++fn)
            bfr[fn] = *(const short8v*)&Bs[(wn * 64 + fn * 16 + lr) * LROW + lg * 8];
#pragma unroll
        for (int fm = 0; fm < 4; ++fm)
#pragma unroll
            for (int fn = 0; fn < 4; ++fn)
                acc[fm][fn] = __builtin_amdgcn_mfma_f32_16x16x32_bf16(
                    a[fm], bfr[fn], acc[fm][fn], 0, 0, 0);
        __syncthreads();
    }

    // ---- epilogue: + bias + task, write fp32 qkv
    const int sel = m0 >> 7;
    const float* __restrict__ task = (sel == 0) ? tq : ((sel == 1) ? tk : tv);
#pragma unroll
    for (int fm = 0; fm < 4; ++fm) {
#pragma unroll
        for (int r = 0; r < 4; ++r) {
            const int m = m0 + wm * 64 + fm * 16 + lg * 4 + r;
            const float bia = bpack[m];
            const int mr = m & (C2 - 1);
#pragma unroll
            for (int fn = 0; fn < 4; ++fn) {
                const int n = n0 + wn * 64 + fn * 16 + lr;
                const float t = task[(size_t)mr * NN + n];
                qkv[((size_t)b * PM + m) * NN + n] = acc[fm][fn][r] + bia + t;
            }
        }
    }
}

// ---------------- Mpart[b][s][i][j] = sum_{n in 128-slice s} K[i][n]*V[j][n]
__global__ __launch_bounds__(256) void k_kv(
    const float* __restrict__ qkv, float* __restrict__ Mpart)
{
    __shared__ float Ks[64][128];   // [nn][i]
    __shared__ float Vs[64][128];   // [nn][j]
    const int b = blockIdx.y;
    const int s = blockIdx.x;       // 0..31
    const int tid = threadIdx.x;
    const int r = tid >> 1;              // row i/j (0..127)
    const int nb = (tid & 1) * 32;       // nn base
    const int ti = tid >> 4, tj = tid & 15;
    const float* __restrict__ Kg = qkv + ((size_t)b * PM + C2) * NN;
    const float* __restrict__ Vg = qkv + ((size_t)b * PM + 2 * C2) * NN;
    float acc[8][8];
#pragma unroll
    for (int i = 0; i < 8; ++i)
#pragma unroll
        for (int j = 0; j < 8; ++j) acc[i][j] = 0.f;

    for (int half = 0; half < 2; ++half) {
        const int n0 = s * 128 + half * 64;
#pragma unroll
        for (int q = 0; q < 8; ++q) {
            const int nn = nb + q * 4;
            float4 kv = *(const float4*)&Kg[(size_t)r * NN + n0 + nn];
            Ks[nn+0][r] = kv.x; Ks[nn+1][r] = kv.y; Ks[nn+2][r] = kv.z; Ks[nn+3][r] = kv.w;
            float4 vv = *(const float4*)&Vg[(size_t)r * NN + n0 + nn];
            Vs[nn+0][r] = vv.x; Vs[nn+1][r] = vv.y; Vs[nn+2][r] = vv.z; Vs[nn+3][r] = vv.w;
        }
        __syncthreads();
        for (int nn = 0; nn < 64; ++nn) {
            float4 a0 = *(const float4*)&Ks[nn][ti * 8];
            float4 a1 = *(const float4*)&Ks[nn][ti * 8 + 4];
            float4 b0 = *(const float4*)&Vs[nn][tj * 8];
            float4 b1 = *(const float4*)&Vs[nn][tj * 8 + 4];
            float a[8] = {a0.x, a0.y, a0.z, a0.w, a1.x, a1.y, a1.z, a1.w};
            float v[8] = {b0.x, b0.y, b0.z, b0.w, b1.x, b1.y, b1.z, b1.w};
#pragma unroll
            for (int ii = 0; ii < 8; ++ii)
#pragma unroll
                for (int jj = 0; jj < 8; ++jj)
                    acc[ii][jj] += a[ii] * v[jj];
        }
        __syncthreads();
    }
    float* __restrict__ Mp = Mpart + ((size_t)b * KVS + s) * C2 * C2;
#pragma unroll
    for (int ii = 0; ii < 8; ++ii) {
        const int row = ti * 8 + ii;
        float4 o0, o1;
        o0.x = acc[ii][0]; o0.y = acc[ii][1]; o0.z = acc[ii][2]; o0.w = acc[ii][3];
        o1.x = acc[ii][4]; o1.y = acc[ii][5]; o1.z = acc[ii][6]; o1.w = acc[ii][7];
        *(float4*)&Mp[row * C2 + tj * 8]     = o0;
        *(float4*)&Mp[row * C2 + tj * 8 + 4] = o1;
    }
}

// ---------------- reduce partials: M[b] = sum_s Mpart[b][s] ---------
__global__ __launch_bounds__(256) void k_kvred(
    const float* __restrict__ Mpart, float* __restrict__ Mb)
{
    const int b = blockIdx.y;
    const int o = (blockIdx.x * 256 + threadIdx.x) * 4;
    const float* __restrict__ p = Mpart + (size_t)b * KVS * C2 * C2 + o;
    float4 acc;
    acc.x = 0.f; acc.y = 0.f; acc.z = 0.f; acc.w = 0.f;
#pragma unroll 4
    for (int s = 0; s < KVS; ++s) {
        float4 v = *(const float4*)&p[(size_t)s * C2 * C2];
        acc.x += v.x; acc.y += v.y; acc.z += v.z; acc.w += v.w;
    }
    *(float4*)&Mb[(size_t)b * C2 * C2 + o] = acc;
}

// ---------------- out3[b][n][j] = sum_i Q[b][i][n] * M[b][i][j] -------------
__global__ __launch_bounds__(256) void k_qm(
    const float* __restrict__ qkv, const float* __restrict__ Mb,
    float* __restrict__ out3)
{
    __shared__ float Qs[128][64];   // [i][n_local]
    __shared__ float Ms[128][64];   // [i][j_local]
    const int b = blockIdx.z;
    const int nbase = blockIdx.x * 64;
    const int jbase = blockIdx.y * 64;
    const int tid = threadIdx.x;
    const int r = tid >> 1;               // i (0..127)
    const int cb = (tid & 1) * 32;
    const float* __restrict__ Qg = qkv + (size_t)b * PM * NN;
    const float* __restrict__ Mg = Mb + (size_t)b * C2 * C2;
#pragma unroll
    for (int q = 0; q < 8; ++q) {
        const int cc = cb + q * 4;
        *(float4*)&Qs[r][cc] = *(const float4*)&Qg[(size_t)r * NN + nbase + cc];
        *(float4*)&Ms[r][cc] = *(const float4*)&Mg[r * C2 + jbase + cc];
    }
    __syncthreads();
    const int tn = tid >> 4, tj = tid & 15;
    float acc[4][4];
#pragma unroll
    for (int i = 0; i < 4; ++i)
#pragma unroll
        for (int j = 0; j < 4; ++j) acc[i][j] = 0.f;
    for (int i = 0; i < 128; ++i) {
        float4 a  = *(const float4*)&Qs[i][tn * 4];
        float4 m4 = *(const float4*)&Ms[i][tj * 4];
        float av[4] = {a.x, a.y, a.z, a.w};
        float mv[4] = {m4.x, m4.y, m4.z, m4.w};
#pragma unroll
        for (int ii = 0; ii < 4; ++ii)
#pragma unroll
            for (int jj = 0; jj < 4; ++jj)
                acc[ii][jj] += av[ii] * mv[jj];
    }
#pragma unroll
    for (int ii = 0; ii < 4; ++ii) {
        float4 o;
        o.x = acc[ii][0]; o.y = acc[ii][1]; o.z = acc[ii][2]; o.w = acc[ii][3];
        *(float4*)&out3[((size_t)b * NN + nbase + tn * 4 + ii) * C2 + jbase + tj * 4] = o;
    }
}

// ---------------- final: out[b][o][p] = X[b][o][p]
//   + sum_c Wo[o][c] * out3[b][c*32 + (p>>7)][p&127] ------------------------
__global__ __launch_bounds__(256) void k_final(
    const float* __restrict__ out3, const float* __restrict__ Wo,
    const float* __restrict__ X, float* __restrict__ out)
{
    __shared__ float Ds[64][128];    // [c_local][j]
    __shared__ float Wos[64][128];   // [c_local][o_local]
    const int g  = blockIdx.x;        // 0..31
    const int o0 = blockIdx.y * 128;  // 0 or 128
    const int b  = blockIdx.z;
    const int tid = threadIdx.x;
    const int to = tid >> 4, tj = tid & 15;
    float acc[8][8];
#pragma unroll
    for (int i = 0; i < 8; ++i)
#pragma unroll
        for (int j = 0; j < 8; ++j) acc[i][j] = 0.f;

    const float* __restrict__ O3 = out3 + (size_t)b * NN * C2;

    for (int ch = 0; ch < 2; ++ch) {
        const int c0 = ch * 64;
        {
            const int r  = tid >> 2;             // c_local 0..63
            const int jb2 = (tid & 3) * 32;
#pragma unroll
            for (int q = 0; q < 8; ++q) {
                const int j = jb2 + q * 4;
                *(float4*)&Ds[r][j] =
                    *(const float4*)&O3[(size_t)((c0 + r) * 32 + g) * C2 + j];
            }
        }
        {
            const int o  = tid >> 1;             // o_local 0..127
            const int cb2 = (tid & 1) * 32;
#pragma unroll
            for (int q = 0; q < 8; ++q) {
                const int cc = cb2 + q * 4;
                float4 w = *(const float4*)&Wo[(size_t)(o0 + o) * C2 + c0 + cc];
                Wos[cc+0][o] = w.x; Wos[cc+1][o] = w.y;
                Wos[cc+2][o] = w.z; Wos[cc+3][o] = w.w;
            }
        }
        __syncthreads();
#pragma unroll
        for (int cc = 0; cc < 64; ++cc) {
            float4 w0 = *(const float4*)&Wos[cc][to * 8];
            float4 w1 = *(const float4*)&Wos[cc][to * 8 + 4];
            float4 d0 = *(const float4*)&Ds[cc][tj * 8];
            float4 d1 = *(const float4*)&Ds[cc][tj * 8 + 4];
            float w[8] = {w0.x, w0.y, w0.z, w0.w, w1.x, w1.y, w1.z, w1.w};
            float d[8] = {d0.x, d0.y, d0.z, d0.w, d1.x, d1.y, d1.z, d1.w};
#pragma unroll
            for (int ii = 0; ii < 8; ++ii)
#pragma unroll
                for (int jj = 0; jj < 8; ++jj)
                    acc[ii][jj] += w[ii] * d[jj];
        }
        __syncthreads();
    }

    const float* __restrict__ Xb = X + (size_t)b * CCH * NN;
    float* __restrict__ Ob = out + (size_t)b * CCH * NN;
#pragma unroll
    for (int oo = 0; oo < 8; ++oo) {
        const int o = o0 + to * 8 + oo;
        const size_t base = (size_t)o * NN + g * 128 + tj * 8;
        float4 x0 = *(const float4*)&Xb[base];
        float4 x1 = *(const float4*)&Xb[base + 4];
        float4 r0, r1;
        r0.x = acc[oo][0] + x0.x; r0.y = acc[oo][1] + x0.y;
        r0.z = acc[oo][2] + x0.z; r0.w = acc[oo][3] + x0.w;
        r1.x = acc[oo][4] + x1.x; r1.y = acc[oo][5] + x1.y;
        r1.z = acc[oo][6] + x1.z; r1.w = acc[oo][7] + x1.w;
        *(float4*)&Ob[base]     = r0;
        *(float4*)&Ob[base + 4] = r1;
    }
}

extern "C" void kernel_launch(void* const* d_in, const int* in_sizes, int n_in,
                              void* d_out, int out_size, void* d_ws, size_t ws_size,
                              hipStream_t stream) {
    const float* X  = (const float*)d_in[0];
    const float* pe = (const float*)d_in[1];
    const float* tq = (const float*)d_in[2];
    const float* tk = (const float*)d_in[3];
    const float* tv = (const float*)d_in[4];
    const float* Wq = (const float*)d_in[5];
    const float* bq = (const float*)d_in[6];
    const float* Wk = (const float*)d_in[7];
    const float* bk = (const float*)d_in[8];
    const float* Wv = (const float*)d_in[9];
    const float* bv = (const float*)d_in[10];
    const float* Wo = (const float*)d_in[11];
    float* out = (float*)d_out;

    // Workspace layout (floats). out3 ALIASES Mpart (same size, disjoint
    // lifetimes: Mpart dead after k_kvred; k_qm then writes out3 — stream order).
    float* ws     = (float*)d_ws;
    float* bpack  = ws;                                   // 512
    short* wpackh = (short*)(ws + 512);                   // 98304 shorts = 49152 floats
    float* qkv    = ws + 512 + 49152;                     // 6291456 -> end 6341120
    float* Mbuf   = qkv + (size_t)BB * PM * NN;           // 65536   -> end 6406656
    float* Mpart  = Mbuf + (size_t)BB * C2 * C2;          // 2097152 -> end 8503808 (34.0 MB)
    float* out3   = Mpart;                                // aliased

    k_pack<<<dim3(PM), dim3(256), 0, stream>>>(Wq, bq, Wk, bk, Wv, bv, wpackh, bpack);
    k_projm<<<dim3(NN / 128, PM / 128, BB), dim3(256), 0, stream>>>(
        X, pe, tq, tk, tv, wpackh, bpack, qkv);
    k_kv<<<dim3(KVS, BB), dim3(256), 0, stream>>>(qkv, Mpart);
    k_kvred<<<dim3(16, BB), dim3(256), 0, stream>>>(Mpart, Mbuf);
    k_qm<<<dim3(NN / 64, 2, BB), dim3(256), 0, stream>>>(qkv, Mbuf, out3);
    k_final<<<dim3(32, 2, BB), dim3(256), 0, stream>>>(out3, Wo, X, out);
}

// Round 5
// 139.334 us; speedup vs baseline: 2.2366x; 1.2178x over previous
//
#include <hip/hip_runtime.h>
#include <cstddef>

// Problem constants
#define BB 4
#define CCH 256     // C
#define C2 128      // C/2
#define NN 4096     // T*H*W
#define PM 384      // 3*C2
#define KVS 16      // split-K slices for K*V^T (256 n each)

typedef __attribute__((ext_vector_type(8))) short short8v;   // 8 bf16
typedef __attribute__((ext_vector_type(4))) short short4v;   // 4 bf16
typedef __attribute__((ext_vector_type(4))) float f32x4;

static __device__ __forceinline__ short f2bf(float f) {
    union { float f; unsigned u; } c; c.f = f;
    unsigned r = (c.u + 0x7FFFu + ((c.u >> 16) & 1u)) >> 16;
    return (short)r;
}

// ---------------- pack W (bf16) + biases + Wo (bf16) ------------------------
__global__ __launch_bounds__(256) void k_pack(
    const float* __restrict__ Wq, const float* __restrict__ bq,
    const float* __restrict__ Wk, const float* __restrict__ bk,
    const float* __restrict__ Wv, const float* __restrict__ bv,
    const float* __restrict__ Wo,
    short* __restrict__ wpackh, float* __restrict__ bpack,
    short* __restrict__ Woh)
{
    const int m = blockIdx.x;     // 0..639
    const int c = threadIdx.x;    // 0..255
    if (m < PM) {
        const float* w; const float* bs; int mm;
        if (m < C2)        { w = Wq; bs = bq; mm = m; }
        else if (m < 2*C2) { w = Wk; bs = bk; mm = m - C2; }
        else               { w = Wv; bs = bv; mm = m - 2*C2; }
        wpackh[m * CCH + c] = f2bf(w[mm * CCH + c]);
        if (c == 0) bpack[m] = bs[mm];
    } else {
        const int o = m - PM;     // 0..255
        if (c < C2) Woh[o * C2 + c] = f2bf(Wo[o * C2 + c]);
    }
}

// ---------------- QKV projection (bf16 MFMA), bf16 outputs ------------------
// qkv[m][n] = sum_c W[m][c]*(X+pe)[c][n] + bias[m] + task[m%128][n]
// Outputs: sel0 -> qt[b][n][i] (transposed), sel1 -> kk[b][i][n], sel2 -> vv.
#define LROW 40
#define TSP  136
__global__ __launch_bounds__(256) void k_projm(
    const float* __restrict__ X, const float* __restrict__ pe,
    const float* __restrict__ tq, const float* __restrict__ tk,
    const float* __restrict__ tv,
    const short* __restrict__ wpackh, const float* __restrict__ bpack,
    short* __restrict__ qt, short* __restrict__ kk, short* __restrict__ vv)
{
    __shared__ short smem[17408];      // max(As+Bs=10240, Ts=128*136=17408)
    short* As = smem;                  // [128 m][40] bf16 (rows of W)
    short* Bs = smem + 5120;           // [128 n][40] bf16 (cols of Xp, [n][k])
    const int b  = blockIdx.z;
    const int m0 = blockIdx.y * 128;   // 0,128,256
    const int n0 = blockIdx.x * 128;
    const int tid  = threadIdx.x;
    const int wave = tid >> 6;
    const int lane = tid & 63;
    const int lr = lane & 15, lg = lane >> 4;
    const int wm = wave >> 1, wn = wave & 1;   // 2x2 wave grid, 64x64 each
    const float* __restrict__ Xb = X + (size_t)b * CCH * NN;

    const int am  = tid >> 1;         // A stage: m row
    const int akb = tid & 1;          // A stage: 16-short half
    const int cq  = tid >> 5;         // B stage: c-quad
    const int nq  = tid & 31;         // B stage: n-quad

    f32x4 acc[4][4];
#pragma unroll
    for (int i = 0; i < 4; ++i)
#pragma unroll
        for (int j = 0; j < 4; ++j) acc[i][j] = (f32x4){0.f, 0.f, 0.f, 0.f};

    for (int k0 = 0; k0 < CCH; k0 += 32) {
        // stage A: 128m x 32k (each thread 16 shorts)
        {
            const size_t gsrc = (size_t)(m0 + am) * CCH + k0 + akb * 16;
            *(short8v*)&As[am * LROW + akb * 16]     = *(const short8v*)&wpackh[gsrc];
            *(short8v*)&As[am * LROW + akb * 16 + 8] = *(const short8v*)&wpackh[gsrc + 8];
        }
        // stage B: transpose 32c x 128n of (X+pe) -> [n][k] bf16
        short sreg[4][4];
#pragma unroll
        for (int j = 0; j < 4; ++j) {
            const int c = k0 + cq * 4 + j;
            const size_t g = (size_t)c * NN + n0 + nq * 4;
            float4 x4 = *(const float4*)&Xb[g];
            float4 p4 = *(const float4*)&pe[g];
            sreg[j][0] = f2bf(x4.x + p4.x);
            sreg[j][1] = f2bf(x4.y + p4.y);
            sreg[j][2] = f2bf(x4.z + p4.z);
            sreg[j][3] = f2bf(x4.w + p4.w);
        }
#pragma unroll
        for (int i = 0; i < 4; ++i) {
            short4v v; v.x = sreg[0][i]; v.y = sreg[1][i]; v.z = sreg[2][i]; v.w = sreg[3][i];
            *(short4v*)&Bs[(nq * 4 + i) * LROW + cq * 4] = v;
        }
        __syncthreads();
        short8v a[4], bfr[4];
#pragma unroll
        for (int fm = 0; fm < 4; ++fm)
            a[fm] = *(const short8v*)&As[(wm * 64 + fm * 16 + lr) * LROW + lg * 8];
#pragma unroll
        for (int fn = 0; fn < 4; ++fn)
            bfr[fn] = *(const short8v*)&Bs[(wn * 64 + fn * 16 + lr) * LROW + lg * 8];
#pragma unroll
        for (int fm = 0; fm < 4; ++fm)
#pragma unroll
            for (int fn = 0; fn < 4; ++fn)
                acc[fm][fn] = __builtin_amdgcn_mfma_f32_16x16x32_bf16(
                    a[fm], bfr[fn], acc[fm][fn], 0, 0, 0);
        __syncthreads();
    }

    // epilogue: + bias + task, bf16, re-layout through LDS (Ts aliases As/Bs;
    // safe: loop ended with __syncthreads()).
    short* Ts = smem;
    const int sel = m0 >> 7;
    if (sel == 0) {
        // Ts[n][m] (short4v writes), readout rows n -> qt[b][n][i]
#pragma unroll
        for (int fm = 0; fm < 4; ++fm)
#pragma unroll
            for (int fn = 0; fn < 4; ++fn) {
                const int n_l  = wn * 64 + fn * 16 + lr;
                const int m_lb = wm * 64 + fm * 16 + lg * 4;
                short4v v;
#pragma unroll
                for (int r = 0; r < 4; ++r) {
                    const int m_l = m_lb + r;
                    v[r] = f2bf(acc[fm][fn][r] + bpack[m_l]
                                + tq[(size_t)m_l * NN + n0 + n_l]);
                }
                *(short4v*)&Ts[n_l * TSP + m_lb] = v;
            }
        __syncthreads();
        const int n_l = tid >> 1, half = tid & 1;
        short* dst = qt + (size_t)b * NN * C2 + (size_t)(n0 + n_l) * C2 + half * 64;
        const short* src = &Ts[n_l * TSP + half * 64];
#pragma unroll
        for (int q2 = 0; q2 < 8; ++q2)
            *(short8v*)&dst[q2 * 8] = *(const short8v*)&src[q2 * 8];
    } else {
        // Ts[m][n] (scalar writes), readout rows m -> kk/vv[b][i][n]
        const float* __restrict__ task = (sel == 1) ? tk : tv;
        short* kv = (sel == 1) ? kk : vv;
#pragma unroll
        for (int fm = 0; fm < 4; ++fm)
#pragma unroll
            for (int fn = 0; fn < 4; ++fn) {
                const int n_l = wn * 64 + fn * 16 + lr;
#pragma unroll
                for (int r = 0; r < 4; ++r) {
                    const int m_l = wm * 64 + fm * 16 + lg * 4 + r;
                    Ts[m_l * TSP + n_l] =
                        f2bf(acc[fm][fn][r] + bpack[m0 + m_l]
                             + task[(size_t)m_l * NN + n0 + n_l]);
                }
            }
        __syncthreads();
        const int m_l = tid >> 1, half = tid & 1;
        short* dst = kv + (size_t)b * C2 * NN + (size_t)m_l * NN + n0 + half * 64;
        const short* src = &Ts[m_l * TSP + half * 64];
#pragma unroll
        for (int q2 = 0; q2 < 8; ++q2)
            *(short8v*)&dst[q2 * 8] = *(const short8v*)&src[q2 * 8];
    }
}

// ---------------- Mpart[b][s] = K-slice · V-slice^T  (MFMA, no LDS) ---------
__global__ __launch_bounds__(256) void k_kv(
    const short* __restrict__ kk, const short* __restrict__ vv,
    float* __restrict__ Mpart)
{
    const int b = blockIdx.y, s = blockIdx.x;
    const int tid = threadIdx.x;
    const int wave = tid >> 6, lane = tid & 63;
    const int lr = lane & 15, lg = lane >> 4;
    const int wi = wave >> 1, wj = wave & 1;
    const short* Kb = kk + (size_t)b * C2 * NN;
    const short* Vb = vv + (size_t)b * C2 * NN;
    const int nbase = s * 256;
    f32x4 acc[4][4];
#pragma unroll
    for (int i = 0; i < 4; ++i)
#pragma unroll
        for (int j = 0; j < 4; ++j) acc[i][j] = (f32x4){0.f, 0.f, 0.f, 0.f};

    for (int ks = 0; ks < 8; ++ks) {
        const int nn = nbase + ks * 32 + lg * 8;
        short8v a[4], bv8[4];
#pragma unroll
        for (int fi = 0; fi < 4; ++fi)
            a[fi] = *(const short8v*)&Kb[(size_t)(wi * 64 + fi * 16 + lr) * NN + nn];
#pragma unroll
        for (int fj = 0; fj < 4; ++fj)
            bv8[fj] = *(const short8v*)&Vb[(size_t)(wj * 64 + fj * 16 + lr) * NN + nn];
#pragma unroll
        for (int fi = 0; fi < 4; ++fi)
#pragma unroll
            for (int fj = 0; fj < 4; ++fj)
                acc[fi][fj] = __builtin_amdgcn_mfma_f32_16x16x32_bf16(
                    a[fi], bv8[fj], acc[fi][fj], 0, 0, 0);
    }
    float* Mp = Mpart + ((size_t)b * KVS + s) * C2 * C2;
#pragma unroll
    for (int fi = 0; fi < 4; ++fi)
#pragma unroll
        for (int fj = 0; fj < 4; ++fj) {
            const int j = wj * 64 + fj * 16 + lr;
#pragma unroll
            for (int r = 0; r < 4; ++r) {
                const int i = wi * 64 + fi * 16 + lg * 4 + r;
                Mp[(size_t)i * C2 + j] = acc[fi][fj][r];
            }
        }
}

// ---------------- reduce partials, emit Mt[b][j][i] bf16 --------------------
__global__ __launch_bounds__(256) void k_kvred(
    const float* __restrict__ Mpart, short* __restrict__ Mt)
{
    const int b = blockIdx.y;
    const int i = blockIdx.x * 16 + (threadIdx.x >> 4);   // grid.x=8 -> i 0..127
    const int j0 = (threadIdx.x & 15) * 8;
    const float* p = Mpart + (size_t)b * KVS * C2 * C2 + (size_t)i * C2 + j0;
    float a8[8];
#pragma unroll
    for (int e = 0; e < 8; ++e) a8[e] = 0.f;
    for (int s = 0; s < KVS; ++s) {
        float4 v0 = *(const float4*)&p[(size_t)s * C2 * C2];
        float4 v1 = *(const float4*)&p[(size_t)s * C2 * C2 + 4];
        a8[0] += v0.x; a8[1] += v0.y; a8[2] += v0.z; a8[3] += v0.w;
        a8[4] += v1.x; a8[5] += v1.y; a8[6] += v1.z; a8[7] += v1.w;
    }
    short* mt = Mt + (size_t)b * C2 * C2;
#pragma unroll
    for (int e = 0; e < 8; ++e)
        mt[(size_t)(j0 + e) * C2 + i] = f2bf(a8[e]);
}

// ---------------- out3[n][j] = sum_i Q[i][n]*M[i][j]  (MFMA, no LDS) --------
// A = Mt[j][i] (rows j, k=i contig), B = qt[n][i] (rows n, k=i contig).
__global__ __launch_bounds__(256) void k_qm(
    const short* __restrict__ qt, const short* __restrict__ Mt,
    short* __restrict__ out3)
{
    const int b = blockIdx.y;
    const int n0 = blockIdx.x * 128;
    const int tid = threadIdx.x;
    const int wave = tid >> 6, lane = tid & 63;
    const int lr = lane & 15, lg = lane >> 4;
    const int wj = wave >> 1, wn = wave & 1;
    const short* Mb = Mt + (size_t)b * C2 * C2;
    const short* Qb = qt + (size_t)b * NN * C2;
    f32x4 acc[4][4];
#pragma unroll
    for (int i = 0; i < 4; ++i)
#pragma unroll
        for (int j = 0; j < 4; ++j) acc[i][j] = (f32x4){0.f, 0.f, 0.f, 0.f};

    for (int ks = 0; ks < 4; ++ks) {
        const int kb = ks * 32 + lg * 8;
        short8v a[4], bq8[4];
#pragma unroll
        for (int fj = 0; fj < 4; ++fj)
            a[fj] = *(const short8v*)&Mb[(size_t)(wj * 64 + fj * 16 + lr) * C2 + kb];
#pragma unroll
        for (int fn = 0; fn < 4; ++fn)
            bq8[fn] = *(const short8v*)&Qb[(size_t)(n0 + wn * 64 + fn * 16 + lr) * C2 + kb];
#pragma unroll
        for (int fj = 0; fj < 4; ++fj)
#pragma unroll
            for (int fn = 0; fn < 4; ++fn)
                acc[fj][fn] = __builtin_amdgcn_mfma_f32_16x16x32_bf16(
                    a[fj], bq8[fn], acc[fj][fn], 0, 0, 0);
    }
    short* O3 = out3 + (size_t)b * NN * C2;
#pragma unroll
    for (int fj = 0; fj < 4; ++fj)
#pragma unroll
        for (int fn = 0; fn < 4; ++fn) {
            const int n  = n0 + wn * 64 + fn * 16 + lr;
            const int jb = wj * 64 + fj * 16 + lg * 4;
            short4v v;
#pragma unroll
            for (int r = 0; r < 4; ++r) v[r] = f2bf(acc[fj][fn][r]);
            *(short4v*)&O3[(size_t)n * C2 + jb] = v;
        }
}

// ---------------- final: out = Wo @ gathered(out3) + X  (MFMA) --------------
// B gathered per-lane from out3 rows (c*32+g); 16-lane-contiguous segments.
__global__ __launch_bounds__(256) void k_final(
    const short* __restrict__ out3, const short* __restrict__ Woh,
    const float* __restrict__ X, float* __restrict__ out)
{
    const int g  = blockIdx.x;        // 0..31
    const int o0 = blockIdx.y * 128;  // 0 or 128
    const int b  = blockIdx.z;
    const int tid = threadIdx.x;
    const int wave = tid >> 6, lane = tid & 63;
    const int lr = lane & 15, lg = lane >> 4;
    const int wm = wave >> 1, wn = wave & 1;
    const short* O3 = out3 + (size_t)b * NN * C2;
    f32x4 acc[4][4];
#pragma unroll
    for (int i = 0; i < 4; ++i)
#pragma unroll
        for (int j = 0; j < 4; ++j) acc[i][j] = (f32x4){0.f, 0.f, 0.f, 0.f};

    for (int ks = 0; ks < 4; ++ks) {
        const int c0 = ks * 32;
        short8v a[4], bb[4];
#pragma unroll
        for (int fm = 0; fm < 4; ++fm)
            a[fm] = *(const short8v*)&Woh[(size_t)(o0 + wm * 64 + fm * 16 + lr) * C2
                                          + c0 + lg * 8];
#pragma unroll
        for (int fn = 0; fn < 4; ++fn) {
            const int pj = wn * 64 + fn * 16 + lr;
            short8v t;
#pragma unroll
            for (int e = 0; e < 8; ++e)
                t[e] = O3[(size_t)((c0 + lg * 8 + e) * 32 + g) * C2 + pj];
            bb[fn] = t;
        }
#pragma unroll
        for (int fm = 0; fm < 4; ++fm)
#pragma unroll
            for (int fn = 0; fn < 4; ++fn)
                acc[fm][fn] = __builtin_amdgcn_mfma_f32_16x16x32_bf16(
                    a[fm], bb[fn], acc[fm][fn], 0, 0, 0);
    }
    const float* Xb = X + (size_t)b * CCH * NN;
    float* Ob = out + (size_t)b * CCH * NN;
#pragma unroll
    for (int fm = 0; fm < 4; ++fm)
#pragma unroll
        for (int fn = 0; fn < 4; ++fn) {
            const int p  = g * 128 + wn * 64 + fn * 16 + lr;
            const int ob = o0 + wm * 64 + fm * 16 + lg * 4;
#pragma unroll
            for (int r = 0; r < 4; ++r) {
                const size_t ad = (size_t)(ob + r) * NN + p;
                Ob[ad] = acc[fm][fn][r] + Xb[ad];
            }
        }
}

extern "C" void kernel_launch(void* const* d_in, const int* in_sizes, int n_in,
                              void* d_out, int out_size, void* d_ws, size_t ws_size,
                              hipStream_t stream) {
    const float* X  = (const float*)d_in[0];
    const float* pe = (const float*)d_in[1];
    const float* tq = (const float*)d_in[2];
    const float* tk = (const float*)d_in[3];
    const float* tv = (const float*)d_in[4];
    const float* Wq = (const float*)d_in[5];
    const float* bq = (const float*)d_in[6];
    const float* Wk = (const float*)d_in[7];
    const float* bk = (const float*)d_in[8];
    const float* Wv = (const float*)d_in[9];
    const float* bv = (const float*)d_in[10];
    const float* Wo = (const float*)d_in[11];
    float* out = (float*)d_out;

    // Workspace (floats): total ~21.4 MB (< proven 34 MB)
    float* ws     = (float*)d_ws;
    float* bpack  = ws;                                  // 512
    short* wpackh = (short*)(ws + 512);                  // 98304 sh
    short* Woh    = (short*)(ws + 512 + 49152);          // 32768 sh
    short* qt     = (short*)(ws + 512 + 49152 + 16384);  // 4*4096*128 sh each:
    short* kk     = qt + (size_t)BB * NN * C2;
    short* vv     = kk + (size_t)BB * NN * C2;
    short* out3   = vv + (size_t)BB * NN * C2;
    short* Mt     = out3 + (size_t)BB * NN * C2;         // 4*128*128 sh
    float* Mpart  = (float*)(Mt + (size_t)BB * C2 * C2); // 4*16*16384 f

    k_pack<<<dim3(PM + CCH), dim3(256), 0, stream>>>(
        Wq, bq, Wk, bk, Wv, bv, Wo, wpackh, bpack, Woh);
    k_projm<<<dim3(NN / 128, 3, BB), dim3(256), 0, stream>>>(
        X, pe, tq, tk, tv, wpackh, bpack, qt, kk, vv);
    k_kv<<<dim3(KVS, BB), dim3(256), 0, stream>>>(kk, vv, Mpart);
    k_kvred<<<dim3(8, BB), dim3(256), 0, stream>>>(Mpart, Mt);
    k_qm<<<dim3(NN / 128, BB), dim3(256), 0, stream>>>(qt, Mt, out3);
    k_final<<<dim3(32, 2, BB), dim3(256), 0, stream>>>(out3, Woh, X, out);
}